// Round 6
// baseline (284.845 us; speedup 1.0000x reference)
//
#include <hip/hip_runtime.h>
#include <hip/hip_bf16.h>
#include <hip/hip_fp16.h>

// Problem constants (fixed by setup_inputs)
#define NQ   5440
#define NB   8
#define DIM  256
#define NH   8
#define CHN  32
#define NLV  4
#define NPT  4
#define MTOT (NB * NQ)   // 43520

typedef __attribute__((ext_vector_type(8))) short s16x8;   // 8 x 16-bit (4 VGPRs)
typedef __attribute__((ext_vector_type(4))) float f32x4;
typedef unsigned short ushort_t;
typedef unsigned int uint_t;

// bf16 weight-buffer segment offsets (elements): [W_val | W_off | W_attn | W_out]
#define WVAL 0
#define WOFF 65536
#define WATT 131072
#define WOUT 163840
#define WTOT 229376

__device__ __forceinline__ short f2bf(float x) {
    union { __hip_bfloat16 b; short s; } u;
    u.b = __float2bfloat16(x);
    return u.s;
}

// async 16B global->LDS copy; LDS dst = wave-uniform base + lane*16
__device__ __forceinline__ void gload_lds16(const void* g, void* l) {
    __builtin_amdgcn_global_load_lds(
        (const __attribute__((address_space(1))) unsigned int*)g,
        (__attribute__((address_space(3))) unsigned int*)l, 16, 0, 0);
}

__device__ __forceinline__ void cvt8b(const float* s, ushort_t* d) {
    f32x4 a = *(const f32x4*)s, b = *(const f32x4*)(s + 4);
    s16x8 v;
#pragma unroll
    for (int e = 0; e < 4; ++e) { v[e] = f2bf(a[e]); v[e + 4] = f2bf(b[e]); }
    *(s16x8*)d = v;
}

// one-time fp32 -> bf16 of the 4 weight matrices (0.9 MB read, ~2 us) [R0]
__global__ __launch_bounds__(256) void cvt_weights(const float* __restrict__ wv,
                                                   const float* __restrict__ wo,
                                                   const float* __restrict__ wa,
                                                   const float* __restrict__ wu,
                                                   ushort_t* __restrict__ wb) {
    const int i = (blockIdx.x * 256 + threadIdx.x) * 8;
    if (i >= WTOT) return;
    const float* src;
    int off;
    if (i < WOFF)      { src = wv; off = WVAL; }
    else if (i < WATT) { src = wo; off = WOFF; }
    else if (i < WOUT) { src = wa; off = WATT; }
    else               { src = wu; off = WOUT; }
    cvt8b(src + (i - off), wb + i);
}

// R0's proven 1-phase GEMM core (fp32 A, fused cvt into staging ds_write;
// W via async DMA). C[m,jloc] = sum_k A[rowBase+m,k]*Wt[jloc,k] + biasT[jloc].
// 128x128 tile, BK=64, 256 threads (2x2 waves), 4x4 16x16x32 bf16 MFMA frags.
// LDS XOR-swizzled in 16B chunks: row r's k-group g at slot (g+r)&7.
__device__ __forceinline__ void gemm_core_f32(const float* __restrict__ A,
                                              const ushort_t* __restrict__ Wt,
                                              const float* __restrict__ biasT,
                                              __half* __restrict__ Ct, int ldC,
                                              int rowBase) {
    __shared__ ushort_t As[128 * 64];   // 16 KB
    __shared__ ushort_t Ws[128 * 64];   // 16 KB

    const int t = threadIdx.x;
    const int lane = t & 63, w = t >> 6;
    const int wm = w >> 1, wn = w & 1;
    const int lr = lane & 15, quad = lane >> 4;

    f32x4 acc[4][4];
#pragma unroll
    for (int i = 0; i < 4; ++i)
#pragma unroll
        for (int j = 0; j < 4; ++j)
#pragma unroll
            for (int r = 0; r < 4; ++r) acc[i][j][r] = 0.f;

    for (int ks = 0; ks < 4; ++ks) {
        if (ks) __syncthreads();
#pragma unroll
        for (int i = 0; i < 4; ++i) {
            const int c = t + i * 256;          // chunk id 0..1023
            const int r = c >> 3, s2 = c & 7;
            const int g = (s2 - r) & 7;         // inverse swizzle
            const int ke = ks * 64 + g * 8;     // element k-offset
            gload_lds16(Wt + (size_t)r * DIM + ke,
                        &Ws[(size_t)(i * 256 + w * 64) * 8]);
            const float* pa = A + (size_t)(rowBase + r) * DIM + ke;
            f32x4 a0 = *(const f32x4*)pa, a1 = *(const f32x4*)(pa + 4);
            s16x8 av;
#pragma unroll
            for (int e = 0; e < 4; ++e) {
                av[e] = f2bf(a0[e]);
                av[e + 4] = f2bf(a1[e]);
            }
            *(s16x8*)&As[(size_t)c * 8] = av;   // slot == chunk id (identity)
        }
        __syncthreads();                        // drains vm+lgkm, barrier
#pragma unroll
        for (int kk = 0; kk < 64; kk += 32) {
            s16x8 afr[4], wfr[4];
            const int G = (kk >> 3) + quad;
#pragma unroll
            for (int i = 0; i < 4; ++i) {
                const int R = wm * 64 + i * 16 + lr;
                afr[i] = *(const s16x8*)&As[(R * 8 + ((G + R) & 7)) * 8];
            }
#pragma unroll
            for (int j = 0; j < 4; ++j) {
                const int R = wn * 64 + j * 16 + lr;
                wfr[j] = *(const s16x8*)&Ws[(R * 8 + ((G + R) & 7)) * 8];
            }
#pragma unroll
            for (int i = 0; i < 4; ++i)
#pragma unroll
                for (int j = 0; j < 4; ++j)
                    acc[i][j] = __builtin_amdgcn_mfma_f32_16x16x32_bf16(
                        afr[i], wfr[j], acc[i][j], 0, 0, 0);
        }
    }

    float bj[4];
#pragma unroll
    for (int j = 0; j < 4; ++j) bj[j] = biasT[wn * 64 + j * 16 + lr];
#pragma unroll
    for (int i = 0; i < 4; ++i)
#pragma unroll
        for (int r = 0; r < 4; ++r) {
            int row = rowBase + wm * 64 + i * 16 + quad * 4 + r;   // D row
#pragma unroll
            for (int j = 0; j < 4; ++j) {
                int col = wn * 64 + j * 16 + lr;                    // D col
                Ct[(size_t)row * ldC + col] = __float2half(acc[i][j][r] + bj[j]);
            }
        }
}

// val (2 col-tiles) + off (2) + attn (1), all f16 out: grid (340, 5)  [R0]
__global__ __launch_bounds__(256) void gemm_fused(const float* __restrict__ inputf,
                                                  const float* __restrict__ query,
                                                  const ushort_t* __restrict__ wb,
                                                  const float* __restrict__ b_val,
                                                  const float* __restrict__ b_off,
                                                  const float* __restrict__ b_attn,
                                                  __half* __restrict__ bval,
                                                  __half* __restrict__ v_off,
                                                  __half* __restrict__ v_attn) {
    const int gy = blockIdx.y;
    const int rowBase = blockIdx.x * 128;
    if (gy < 2)
        gemm_core_f32(inputf, wb + WVAL + (size_t)gy * 128 * DIM,
                      b_val + gy * 128, bval + gy * 128, DIM, rowBase);
    else if (gy < 4)
        gemm_core_f32(query, wb + WOFF + (size_t)(gy - 2) * 128 * DIM,
                      b_off + (gy - 2) * 128, v_off + (gy - 2) * 128, DIM, rowBase);
    else
        gemm_core_f32(query, wb + WATT, b_attn, v_attn, 128, rowBase);
}

// Fused sampling + output GEMM. One block = 64 queries of ONE batch.
// Grid 680 = 8 batches x 85 panels (5440/64 exactly); n = blockIdx&7 keeps the
// R0-proven per-XCD bval L2 affinity; pan = blockIdx>>3.
// LDS 48 KB -> 3 blocks/CU; in-flight queries/CU while sampling = 3 blk x 8 q
// = 24 (R0: ~25; R1's bad regime: 46). 680 <= 768 resident -> no tail.
// Sampling: 8 iters x (2 sub-groups x 4 queries), R0 math + R1's validated
// packed-uint4 item format (scratch 16 KB, overlaid on the W-staging area).
// Results -> samp[64][256] bf16 in LDS (XOR-swizzled 16B chunks: chunk c of
// row r at slot c^(r&7) within its 8-group) — kills the sampb global
// round-trip (44.6 MB).
// GEMM: M=64 x N=256 x K=256; A-frags straight from samp LDS; W_out staged
// per 128-col half via the proven DMA+swizzle path (Ws 16 KB, BK=64).
__global__ __launch_bounds__(256) void sample_out(
    const float* __restrict__ refp,            // (N, Lq, L, 2)
    const __half* __restrict__ off,            // (N*Lq, 256) f16
    const __half* __restrict__ attn,           // (N*Lq, 128) f16
    const __half* __restrict__ bval,           // (N, Lin, 256) f16, d = h*32+c
    const int* __restrict__ shapes,            // (L, 2) [H, W]
    const int* __restrict__ starts,            // (L,)
    const ushort_t* __restrict__ wb,           // bf16 weights (uses WOUT seg)
    const float* __restrict__ b_out,
    float* __restrict__ out)                   // (N*Lq, 256) f32
{
    __shared__ __align__(16) char smem[49152];         // 48 KB
    ushort_t* samp = (ushort_t*)smem;                  // [64][256] bf16, 32 KB
    ushort_t* Ws   = (ushort_t*)(smem + 32768);        // [128][64] bf16, 16 KB
    uint4*  scratch = (uint4*)(smem + 32768);          // 1024 items (sampling)

    const int n = blockIdx.x & 7;
    const int pan = blockIdx.x >> 3;                   // 0..84
    const int t = threadIdx.x;
    const int tl = t & 127, sub = t >> 7;

    // ---------------- sampling: 8 iterations x 8 queries --------------------
    for (int it8 = 0; it8 < 8; ++it8) {
        const int qBase = n * NQ + pan * 64 + it8 * 8 + sub * 4;
        __syncthreads();                               // scratch safe for reuse
#pragma unroll
        for (int it = 0; it < 4; ++it) {
            const int i = tl + it * 128;               // item 0..511 (this sub)
            const int q4 = i >> 7, hlp = i & 127;
            const int h = hlp >> 4, lp = hlp & 15, l = lp >> 2;
            const int q = qBase + q4;
            const int Wl = shapes[2 * l + 1], Hl = shapes[2 * l];
            const float Wf = (float)Wl, Hf = (float)Hl;
            const float2 rp = *(const float2*)(refp + ((size_t)q * NLV + l) * 2);
            const __half2 oo2 = ((const __half2*)off)[(size_t)q * 128 + h * 16 + lp];
            const float2 oo = __half22float2(oo2);
            const float x = (rp.x + oo.x / Wf) * Wf - 0.5f;
            const float y = (rp.y + oo.y / Hf) * Hf - 0.5f;

            float logit = __half2float(attn[(size_t)q * 128 + h * 16 + lp]);
            float m = logit;
#pragma unroll
            for (int s = 8; s >= 1; s >>= 1) m = fmaxf(m, __shfl_xor(m, s, 16));
            float e = __expf(logit - m);
            float ss = e;
#pragma unroll
            for (int s = 8; s >= 1; s >>= 1) ss += __shfl_xor(ss, s, 16);
            const float aw = e / ss;

            const float xf = floorf(x), yf = floorf(y);
            const int ix = (int)xf, iy = (int)yf;
            const float wx = x - xf, wy = y - yf;
            const int ix1 = ix + 1, iy1 = iy + 1;
            const bool bx0 = (ix >= 0) & (ix < Wl);
            const bool bx1 = (ix1 >= 0) & (ix1 < Wl);
            const bool by0 = (iy >= 0) & (iy < Hl);
            const bool by1 = (iy1 >= 0) & (iy1 < Hl);
            const int cx0 = min(max(ix, 0), Wl - 1), cx1 = min(max(ix1, 0), Wl - 1);
            const int cy0 = min(max(iy, 0), Hl - 1), cy1 = min(max(iy1, 0), Hl - 1);
            const int base = n * NQ + starts[l];

            uint4 item;                                // R1-validated packing
            item.x = (uint_t)(base + cy0 * Wl + cx0) << 9;       // byte offset
            const uint_t dx  = (uint_t)(cx1 - cx0) << 9;         // 0 or 512
            const uint_t dyW = (uint_t)((cy1 - cy0) * Wl) << 9;  // <= 32768
            item.y = dx | (dyW << 16);
            union { __half2 h; uint_t u; } p01, p23;
            p01.h = __halves2half2(
                __float2half((bx0 && by0) ? aw * (1.f - wx) * (1.f - wy) : 0.f),
                __float2half((bx1 && by0) ? aw * wx * (1.f - wy) : 0.f));
            p23.h = __halves2half2(
                __float2half((bx0 && by1) ? aw * (1.f - wx) * wy : 0.f),
                __float2half((bx1 && by1) ? aw * wx * wy : 0.f));
            item.z = p01.u;
            item.w = p23.u;
            scratch[sub * 512 + i] = item;
        }
        __syncthreads();

        const int q4 = tl >> 5, r = tl & 31;
        const int h = r >> 2, cg = r & 3;              // 8 channels per thread
        const char* vb = (const char*)bval + h * 64 + cg * 16;
        const int slotBase = sub * 512 + (q4 << 7) + (h << 4);

        __half2 acch[4];
        float accf[8];
#pragma unroll
        for (int e = 0; e < 4; ++e) acch[e] = __float2half2_rn(0.f);
#pragma unroll
        for (int e = 0; e < 8; ++e) accf[e] = 0.f;

#pragma unroll
        for (int j = 0; j < 16; ++j) {
            const int lp = (j + h) & 15;               // per-head rotation
            const uint4 itv = scratch[slotBase + lp];
            const uint_t a00 = itv.x;
            const uint_t dx = itv.y & 0xffffu, dyW = itv.y >> 16;
            uint_t ad[4];
            ad[0] = a00;
            ad[1] = a00 + dx;
            ad[2] = a00 + dyW;
            ad[3] = a00 + dx + dyW;
            union { uint_t u; __half2 h; } w01, w23;
            w01.u = itv.z; w23.u = itv.w;
            __half2 wc[4];
            wc[0] = __half2half2(__low2half(w01.h));
            wc[1] = __half2half2(__high2half(w01.h));
            wc[2] = __half2half2(__low2half(w23.h));
            wc[3] = __half2half2(__high2half(w23.h));

            uint4 u[4];
#pragma unroll
            for (int c = 0; c < 4; ++c)
                u[c] = *(const uint4*)(vb + (size_t)ad[c]);
#pragma unroll
            for (int c = 0; c < 4; ++c) {
                const __half2* hv = (const __half2*)&u[c];
#pragma unroll
                for (int e = 0; e < 4; ++e) acch[e] = __hfma2(hv[e], wc[c], acch[e]);
            }
            if ((j & 3) == 3) {
#pragma unroll
                for (int e = 0; e < 4; ++e) {
                    float2 f = __half22float2(acch[e]);
                    accf[2 * e] += f.x;
                    accf[2 * e + 1] += f.y;
                    acch[e] = __float2half2_rn(0.f);
                }
            }
        }

        s16x8 o;
#pragma unroll
        for (int e = 0; e < 8; ++e) o[e] = f2bf(accf[e]);
        const int row = it8 * 8 + sub * 4 + q4;        // local query row 0..63
        const int cs = (h * 4 + cg) ^ (row & 7);       // swizzled 16B chunk
        *(s16x8*)&samp[row * 256 + cs * 8] = o;
    }

    // ---------------- output GEMM: out[64 x 256] = samp @ W_out^T + b -------
    const int lane = t & 63, w = t >> 6;
    const int wm = w >> 1, wn = w & 1;
    const int lr = lane & 15, quad = lane >> 4;

#pragma unroll 1
    for (int jn = 0; jn < 2; ++jn) {
        const ushort_t* Wt = wb + WOUT + (size_t)jn * 128 * DIM;
        f32x4 acc[2][4];
#pragma unroll
        for (int i = 0; i < 2; ++i)
#pragma unroll
            for (int j = 0; j < 4; ++j)
#pragma unroll
                for (int rr = 0; rr < 4; ++rr) acc[i][j][rr] = 0.f;

        for (int ks = 0; ks < 4; ++ks) {
            __syncthreads();                   // samp done / Ws reusable
#pragma unroll
            for (int i = 0; i < 4; ++i) {
                const int c = t + i * 256;     // chunk id 0..1023
                const int rw = c >> 3, s2 = c & 7;
                const int g = (s2 - rw) & 7;   // inverse swizzle
                const int ke = ks * 64 + g * 8;
                gload_lds16(Wt + (size_t)rw * DIM + ke,
                            &Ws[(size_t)(i * 256 + w * 64) * 8]);
            }
            __syncthreads();                   // drains vm, barrier
#pragma unroll
            for (int kk = 0; kk < 64; kk += 32) {
                s16x8 afr[2], wfr[4];
                const int G = (kk >> 3) + quad;
#pragma unroll
                for (int i = 0; i < 2; ++i) {
                    const int R = wm * 32 + i * 16 + lr;
                    const int kc = ks * 8 + G;          // chunk 0..31
                    afr[i] = *(const s16x8*)&samp[R * 256 + (kc ^ (R & 7)) * 8];
                }
#pragma unroll
                for (int j = 0; j < 4; ++j) {
                    const int R = wn * 64 + j * 16 + lr;
                    wfr[j] = *(const s16x8*)&Ws[(R * 8 + ((G + R) & 7)) * 8];
                }
#pragma unroll
                for (int i = 0; i < 2; ++i)
#pragma unroll
                    for (int j = 0; j < 4; ++j)
                        acc[i][j] = __builtin_amdgcn_mfma_f32_16x16x32_bf16(
                            afr[i], wfr[j], acc[i][j], 0, 0, 0);
            }
        }

        float bj[4];
#pragma unroll
        for (int j = 0; j < 4; ++j) bj[j] = b_out[jn * 128 + wn * 64 + j * 16 + lr];
#pragma unroll
        for (int i = 0; i < 2; ++i)
#pragma unroll
            for (int rr = 0; rr < 4; ++rr) {
                const int q = n * NQ + pan * 64 + wm * 32 + i * 16 + quad * 4 + rr;
#pragma unroll
                for (int j = 0; j < 4; ++j) {
                    const int col = jn * 128 + wn * 64 + j * 16 + lr;
                    out[(size_t)q * DIM + col] = acc[i][j][rr] + bj[j];
                }
            }
    }
}

extern "C" void kernel_launch(void* const* d_in, const int* in_sizes, int n_in,
                              void* d_out, int out_size, void* d_ws, size_t ws_size,
                              hipStream_t stream) {
    const float* query  = (const float*)d_in[0];
    const float* refp   = (const float*)d_in[1];
    const float* inputf = (const float*)d_in[2];
    const int* shapes   = (const int*)d_in[3];
    const int* starts   = (const int*)d_in[4];
    const float* W_off  = (const float*)d_in[5];
    const float* b_off  = (const float*)d_in[6];
    const float* W_attn = (const float*)d_in[7];
    const float* b_attn = (const float*)d_in[8];
    const float* W_val  = (const float*)d_in[9];
    const float* b_val  = (const float*)d_in[10];
    const float* W_out  = (const float*)d_in[11];
    const float* b_out  = (const float*)d_in[12];
    float* out = (float*)d_out;

    // workspace (bytes): wb(bf16) | bval(f16) | v_off(f16) | v_attn(f16)
    const size_t AB = (size_t)MTOT * DIM * 2;   // 22,282,240
    char* ws = (char*)d_ws;
    ushort_t* wb     = (ushort_t*)ws;                                   // 0.46 MB
    __half*   bval   = (__half*)(ws + 512 * 1024);
    __half*   v_off  = (__half*)(ws + 512 * 1024 + AB);
    __half*   v_attn = (__half*)(ws + 512 * 1024 + 2 * AB);

    cvt_weights<<<dim3(WTOT / 2048), dim3(256), 0, stream>>>(W_val, W_off, W_attn,
                                                             W_out, wb);
    gemm_fused<<<dim3(MTOT / 128, 5), dim3(256), 0, stream>>>(
        inputf, query, wb, b_val, b_off, b_attn, bval, v_off, v_attn);
    sample_out<<<dim3(MTOT / 64), dim3(256), 0, stream>>>(
        refp, v_off, v_attn, bval, shapes, starts, wb, b_out, out);
}

// Round 7
// 256.577 us; speedup vs baseline: 1.1102x; 1.1102x over previous
//
#include <hip/hip_runtime.h>
#include <hip/hip_bf16.h>
#include <hip/hip_fp16.h>

// Problem constants (fixed by setup_inputs)
#define NQ   5440
#define NB   8
#define DIM  256
#define NH   8
#define CHN  32
#define NLV  4
#define NPT  4
#define MTOT (NB * NQ)   // 43520

typedef __attribute__((ext_vector_type(8))) short s16x8;   // 8 x 16-bit (4 VGPRs)
typedef __attribute__((ext_vector_type(4))) float f32x4;
typedef unsigned short ushort_t;

// bf16 weight-buffer segment offsets (elements): [W_val | W_off | W_attn | W_out]
#define WVAL 0
#define WOFF 65536
#define WATT 131072
#define WOUT 163840
#define WTOT 229376

__device__ __forceinline__ short f2bf(float x) {
    union { __hip_bfloat16 b; short s; } u;
    u.b = __float2bfloat16(x);
    return u.s;
}

// async 16B global->LDS copy; LDS dst = wave-uniform base + lane*16
__device__ __forceinline__ void gload_lds16(const void* g, void* l) {
    __builtin_amdgcn_global_load_lds(
        (const __attribute__((address_space(1))) unsigned int*)g,
        (__attribute__((address_space(3))) unsigned int*)l, 16, 0, 0);
}

__device__ __forceinline__ void cvt8b(const float* s, ushort_t* d) {
    f32x4 a = *(const f32x4*)s, b = *(const f32x4*)(s + 4);
    s16x8 v;
#pragma unroll
    for (int e = 0; e < 4; ++e) { v[e] = f2bf(a[e]); v[e + 4] = f2bf(b[e]); }
    *(s16x8*)d = v;
}

// one-time fp32 -> bf16 of the 4 weight matrices (0.9 MB read, ~2 us)
__global__ __launch_bounds__(256) void cvt_weights(const float* __restrict__ wv,
                                                   const float* __restrict__ wo,
                                                   const float* __restrict__ wa,
                                                   const float* __restrict__ wu,
                                                   ushort_t* __restrict__ wb) {
    const int i = (blockIdx.x * 256 + threadIdx.x) * 8;
    if (i >= WTOT) return;
    const float* src;
    int off;
    if (i < WOFF)      { src = wv; off = WVAL; }
    else if (i < WATT) { src = wo; off = WOFF; }
    else if (i < WOUT) { src = wa; off = WATT; }
    else               { src = wu; off = WOUT; }
    cvt8b(src + (i - off), wb + i);
}

__device__ __forceinline__ void stC(float* p, float v) { *p = v; }
__device__ __forceinline__ void stC(__half* p, float v) { *p = __float2half(v); }
__device__ __forceinline__ void stC(ushort_t* p, float v) { *(short*)p = f2bf(v); }

// C[m, jloc] = sum_k A[rowBase+m, k] * Wt[jloc, k] + biasT[jloc]
// 128x128 tile, BK=64, 256 threads (2x2 waves), 4x4 16x16x32 bf16 MFMA frags.
// LDS layout XOR-swizzled in 16B chunks: row r's k-group g lives at slot
// (g+r)&7 (row = 128B = 8 chunks). Staging writes are lane-consecutive 16B
// (conflict-free); fragment ds_read_b128 hits 8 bank-groups, 2-way alias
// (free). A path: fp32 source, cvt fused into staging ds_write. bf16 source:
// async global_load_lds (identity lane->chunk placement, inverse-swizzled
// source address).
template <typename AT, typename CT>
__device__ __forceinline__ void gemm_core(const AT* __restrict__ A,
                                          const ushort_t* __restrict__ Wt,
                                          const float* __restrict__ biasT,
                                          CT* __restrict__ Ct, int ldC, int rowBase) {
    __shared__ ushort_t As[128 * 64];   // 16 KB
    __shared__ ushort_t Ws[128 * 64];   // 16 KB

    const int t = threadIdx.x;
    const int lane = t & 63, w = t >> 6;
    const int wm = w >> 1, wn = w & 1;
    const int lr = lane & 15, quad = lane >> 4;

    f32x4 acc[4][4];
#pragma unroll
    for (int i = 0; i < 4; ++i)
#pragma unroll
        for (int j = 0; j < 4; ++j)
#pragma unroll
            for (int r = 0; r < 4; ++r) acc[i][j][r] = 0.f;

    for (int ks = 0; ks < 4; ++ks) {
        if (ks) __syncthreads();
#pragma unroll
        for (int i = 0; i < 4; ++i) {
            const int c = t + i * 256;          // chunk id 0..1023
            const int r = c >> 3, s = c & 7;
            const int g = (s - r) & 7;          // inverse swizzle
            const int ke = ks * 64 + g * 8;     // element k-offset
            gload_lds16(Wt + (size_t)r * DIM + ke,
                        &Ws[(size_t)(i * 256 + w * 64) * 8]);
            if constexpr (sizeof(AT) == 2) {
                gload_lds16(A + (size_t)(rowBase + r) * DIM + ke,
                            &As[(size_t)(i * 256 + w * 64) * 8]);
            } else {
                const float* pa = (const float*)A + (size_t)(rowBase + r) * DIM + ke;
                f32x4 a0 = *(const f32x4*)pa, a1 = *(const f32x4*)(pa + 4);
                s16x8 av;
#pragma unroll
                for (int e = 0; e < 4; ++e) {
                    av[e] = f2bf(a0[e]);
                    av[e + 4] = f2bf(a1[e]);
                }
                *(s16x8*)&As[(size_t)c * 8] = av;   // slot == chunk id (identity)
            }
        }
        __syncthreads();                        // drains vm+lgkm, barrier
#pragma unroll
        for (int kk = 0; kk < 64; kk += 32) {
            s16x8 afr[4], wfr[4];
            const int G = (kk >> 3) + quad;
#pragma unroll
            for (int i = 0; i < 4; ++i) {
                const int R = wm * 64 + i * 16 + lr;
                afr[i] = *(const s16x8*)&As[(R * 8 + ((G + R) & 7)) * 8];
            }
#pragma unroll
            for (int j = 0; j < 4; ++j) {
                const int R = wn * 64 + j * 16 + lr;
                wfr[j] = *(const s16x8*)&Ws[(R * 8 + ((G + R) & 7)) * 8];
            }
#pragma unroll
            for (int i = 0; i < 4; ++i)
#pragma unroll
                for (int j = 0; j < 4; ++j)
                    acc[i][j] = __builtin_amdgcn_mfma_f32_16x16x32_bf16(
                        afr[i], wfr[j], acc[i][j], 0, 0, 0);
        }
    }

    float bj[4];
#pragma unroll
    for (int j = 0; j < 4; ++j) bj[j] = biasT[wn * 64 + j * 16 + lr];
#pragma unroll
    for (int i = 0; i < 4; ++i)
#pragma unroll
        for (int r = 0; r < 4; ++r) {
            int row = rowBase + wm * 64 + i * 16 + quad * 4 + r;   // D row
#pragma unroll
            for (int j = 0; j < 4; ++j) {
                int col = wn * 64 + j * 16 + lr;                    // D col
                stC(&Ct[(size_t)row * ldC + col], acc[i][j][r] + bj[j]);
            }
        }
}

// val (2 col-tiles) + off (2) + attn (1), all f16 out: grid (340, 5)
__global__ __launch_bounds__(256) void gemm_fused(const float* __restrict__ inputf,
                                                  const float* __restrict__ query,
                                                  const ushort_t* __restrict__ wb,
                                                  const float* __restrict__ b_val,
                                                  const float* __restrict__ b_off,
                                                  const float* __restrict__ b_attn,
                                                  __half* __restrict__ bval,
                                                  __half* __restrict__ v_off,
                                                  __half* __restrict__ v_attn) {
    const int gy = blockIdx.y;
    const int rowBase = blockIdx.x * 128;
    if (gy < 2)
        gemm_core<float, __half>(inputf, wb + WVAL + (size_t)gy * 128 * DIM,
                                 b_val + gy * 128, bval + gy * 128, DIM, rowBase);
    else if (gy < 4)
        gemm_core<float, __half>(query, wb + WOFF + (size_t)(gy - 2) * 128 * DIM,
                                 b_off + (gy - 2) * 128, v_off + (gy - 2) * 128, DIM,
                                 rowBase);
    else
        gemm_core<float, __half>(query, wb + WATT, b_attn, v_attn, 128, rowBase);
}

__global__ __launch_bounds__(256) void gemm_out(const ushort_t* __restrict__ A,
                                                const ushort_t* __restrict__ wb,
                                                const float* __restrict__ bias,
                                                float* __restrict__ C) {
    gemm_core<ushort_t, float>(A, wb + WOUT + (size_t)blockIdx.y * 128 * DIM,
                               bias + blockIdx.y * 128, C + blockIdx.y * 128, DIM,
                               blockIdx.x * 128);
}

// One block per 4 queries, 128 threads. XCD-aware: batch n = blockIdx.x & 7
// matches the round-robin block->XCD mapping, so each XCD's L2 holds one
// batch's value plane (2.8 MB f16 < 4 MB L2).
// NOTE (R1/R6 post-mortems): raising resident queries/CU (R1: 46) thrashes
// the per-XCD L2 (bval evicted, FETCH +22 MB, slower); fusing GEMM into this
// kernel (R6) collapses TLP. Keep this structure; optimize per-thread ILP.
// R7: phase-B gather ILP. At R0's VGPR_Count=48 the compiler could hold ~1
// j-iteration's 4 uint4 gathers in flight -> 16 serial ~200cy L2 round-trips
// per thread dominate. Process j in PAIRS: read both LDS items, issue all 8
// uint4 gathers back-to-back, then consume in the exact original hfma2 order
// (accumulation order unchanged -> bit-identical result). launch_bounds
// (128,4) lifts the VGPR cap for the 8 in-flight uint4s; LDS still caps
// occupancy at 10 blocks/CU, unchanged.
// Phase A (128 thr x 4 items = 512 = q4*h*l*p): coords + softmax + corner BYTE
//   offsets + packed-half2 weights -> LDS at slot = item idx (16B b128 writes).
// Phase B: thread = (q4, h, cg): 8 f16 channels per corner via uint4 loads;
//   4 v_pk_fma_f16 per corner; f32 flush every 4 j-iterations.
__global__ __launch_bounds__(128, 4) void sample_kernel(
    const float* __restrict__ refp,            // (N, Lq, L, 2)
    const __half* __restrict__ off,            // (N*Lq, 256) f16
    const __half* __restrict__ attn,           // (N*Lq, 128) f16
    const __half* __restrict__ bval,           // (N, Lin, 256) f16, d = h*32+c
    const int* __restrict__ shapes,            // (L, 2) [H, W]
    const int* __restrict__ starts,            // (L,)
    ushort_t* __restrict__ sampb)              // (N*Lq, 256) bf16
{
    const int n = blockIdx.x & 7;
    const int qBase = n * NQ + (blockIdx.x >> 3) * 4;
    const int t = threadIdx.x;

    __shared__ __align__(16) int     sidx[512][4];   // 8 KB
    __shared__ __align__(16) __half2 sww[512][4];    // 8 KB

#pragma unroll
    for (int it = 0; it < 4; ++it) {
        const int i = t + it * 128;
        const int q4 = i >> 7, hlp = i & 127;
        const int h = hlp >> 4, lp = hlp & 15, l = lp >> 2;
        const int q = qBase + q4;
        const int Wl = shapes[2 * l + 1], Hl = shapes[2 * l];
        const float Wf = (float)Wl, Hf = (float)Hl;
        const float2 rp = *(const float2*)(refp + ((size_t)q * NLV + l) * 2);
        const __half2 oo2 = ((const __half2*)off)[(size_t)q * 128 + h * 16 + lp];
        const float2 oo = __half22float2(oo2);
        const float x = (rp.x + oo.x / Wf) * Wf - 0.5f;
        const float y = (rp.y + oo.y / Hf) * Hf - 0.5f;

        float logit = __half2float(attn[(size_t)q * 128 + h * 16 + lp]);
        float m = logit;
#pragma unroll
        for (int s = 8; s >= 1; s >>= 1) m = fmaxf(m, __shfl_xor(m, s, 16));
        float e = __expf(logit - m);
        float ss = e;
#pragma unroll
        for (int s = 8; s >= 1; s >>= 1) ss += __shfl_xor(ss, s, 16);
        const float aw = e / ss;

        const float xf = floorf(x), yf = floorf(y);
        const int ix = (int)xf, iy = (int)yf;
        const float wx = x - xf, wy = y - yf;
        const int ix1 = ix + 1, iy1 = iy + 1;
        const bool bx0 = (ix >= 0) & (ix < Wl);
        const bool bx1 = (ix1 >= 0) & (ix1 < Wl);
        const bool by0 = (iy >= 0) & (iy < Hl);
        const bool by1 = (iy1 >= 0) & (iy1 < Hl);
        const int cx0 = min(max(ix, 0), Wl - 1), cx1 = min(max(ix1, 0), Wl - 1);
        const int cy0 = min(max(iy, 0), Hl - 1), cy1 = min(max(iy1, 0), Hl - 1);
        const int base = n * NQ + starts[l];
        int4 id;
        id.x = (base + cy0 * Wl + cx0) << 9;   // byte offset (row stride 512B)
        id.y = (base + cy0 * Wl + cx1) << 9;
        id.z = (base + cy1 * Wl + cx0) << 9;
        id.w = (base + cy1 * Wl + cx1) << 9;
        __half2 wp[4];
        wp[0] = __float2half2_rn((bx0 && by0) ? aw * (1.f - wx) * (1.f - wy) : 0.f);
        wp[1] = __float2half2_rn((bx1 && by0) ? aw * wx * (1.f - wy) : 0.f);
        wp[2] = __float2half2_rn((bx0 && by1) ? aw * (1.f - wx) * wy : 0.f);
        wp[3] = __float2half2_rn((bx1 && by1) ? aw * wx * wy : 0.f);
        *(int4*)sidx[i] = id;
        *(uint4*)&sww[i][0] = *(uint4*)wp;
    }
    __syncthreads();

    const int q4 = t >> 5, r = t & 31;
    const int h = r >> 2, cg = r & 3;           // 8 channels per thread
    const int q = qBase + q4;
    const char* vb = (const char*)bval + h * 64 + cg * 16;
    const int slotBase = (q4 << 7) + (h << 4);

    __half2 acch[4];
    float accf[8];
#pragma unroll
    for (int e = 0; e < 4; ++e) acch[e] = __float2half2_rn(0.f);
#pragma unroll
    for (int e = 0; e < 8; ++e) accf[e] = 0.f;

#pragma unroll
    for (int jp = 0; jp < 8; ++jp) {
        const int j0 = 2 * jp;
        const int lpA = (j0 + h) & 15;          // per-head rotation
        const int lpB = (j0 + 1 + h) & 15;
        const int4 idA = *(const int4*)sidx[slotBase + lpA];
        const uint4 wuA = *(const uint4*)&sww[slotBase + lpA][0];
        const int4 idB = *(const int4*)sidx[slotBase + lpB];
        const uint4 wuB = *(const uint4*)&sww[slotBase + lpB][0];
        int idc[8] = {idA.x, idA.y, idA.z, idA.w, idB.x, idB.y, idB.z, idB.w};
        uint4 u[8];
#pragma unroll
        for (int c = 0; c < 8; ++c)             // 8 gathers in flight
            u[c] = *(const uint4*)(vb + (size_t)(unsigned)idc[c]);
        const __half2* wpA = (const __half2*)&wuA;
        const __half2* wpB = (const __half2*)&wuB;
#pragma unroll
        for (int c = 0; c < 4; ++c) {           // j0: original order
            const __half2* hv = (const __half2*)&u[c];
#pragma unroll
            for (int e = 0; e < 4; ++e) acch[e] = __hfma2(hv[e], wpA[c], acch[e]);
        }
#pragma unroll
        for (int c = 0; c < 4; ++c) {           // j0+1: original order
            const __half2* hv = (const __half2*)&u[4 + c];
#pragma unroll
            for (int e = 0; e < 4; ++e) acch[e] = __hfma2(hv[e], wpB[c], acch[e]);
        }
        if (jp & 1) {                           // after j = 3, 7, 11, 15
#pragma unroll
            for (int e = 0; e < 4; ++e) {
                float2 f = __half22float2(acch[e]);
                accf[2 * e] += f.x;
                accf[2 * e + 1] += f.y;
                acch[e] = __float2half2_rn(0.f);
            }
        }
    }

    s16x8 o;
#pragma unroll
    for (int e = 0; e < 8; ++e) o[e] = f2bf(accf[e]);
    *(s16x8*)(sampb + (size_t)q * DIM + h * CHN + cg * 8) = o;
}

extern "C" void kernel_launch(void* const* d_in, const int* in_sizes, int n_in,
                              void* d_out, int out_size, void* d_ws, size_t ws_size,
                              hipStream_t stream) {
    const float* query  = (const float*)d_in[0];
    const float* refp   = (const float*)d_in[1];
    const float* inputf = (const float*)d_in[2];
    const int* shapes   = (const int*)d_in[3];
    const int* starts   = (const int*)d_in[4];
    const float* W_off  = (const float*)d_in[5];
    const float* b_off  = (const float*)d_in[6];
    const float* W_attn = (const float*)d_in[7];
    const float* b_attn = (const float*)d_in[8];
    const float* W_val  = (const float*)d_in[9];
    const float* b_val  = (const float*)d_in[10];
    const float* W_out  = (const float*)d_in[11];
    const float* b_out  = (const float*)d_in[12];
    float* out = (float*)d_out;

    // workspace (bytes): wb(bf16) | bval(f16) | v_off(f16) | v_attn(f16) | sampb(bf16)
    const size_t AB = (size_t)MTOT * DIM * 2;   // 22,282,240
    char* ws = (char*)d_ws;
    ushort_t* wb     = (ushort_t*)ws;                                   // 0.46 MB
    __half*   bval   = (__half*)(ws + 512 * 1024);
    __half*   v_off  = (__half*)(ws + 512 * 1024 + AB);
    __half*   v_attn = (__half*)(ws + 512 * 1024 + 2 * AB);
    ushort_t* sampb  = (ushort_t*)(ws + 512 * 1024 + 2 * AB + AB / 2);

    cvt_weights<<<dim3(WTOT / 2048), dim3(256), 0, stream>>>(W_val, W_off, W_attn,
                                                             W_out, wb);
    gemm_fused<<<dim3(MTOT / 128, 5), dim3(256), 0, stream>>>(
        inputf, query, wb, b_val, b_off, b_attn, bval, v_off, v_attn);
    sample_kernel<<<dim3(MTOT / 4), dim3(128), 0, stream>>>(
        refp, v_off, v_attn, bval, shapes, starts, sampb);
    gemm_out<<<dim3(MTOT / 128, 2), dim3(256), 0, stream>>>(sampb, wb, b_out, out);
}